// Round 8
// baseline (129.565 us; speedup 1.0000x reference)
//
#include <hip/hip_runtime.h>
#include <hip/hip_bf16.h>

typedef __bf16 bf16_t;
typedef bf16_t bf16x8 __attribute__((ext_vector_type(8)));
typedef bf16_t bf16x4 __attribute__((ext_vector_type(4)));
typedef float f32x4 __attribute__((ext_vector_type(4)));

#define MFMA16(a, b, c) __builtin_amdgcn_mfma_f32_16x16x32_bf16((a), (b), (c), 0, 0, 0)

// B=8, T=2048, E=1024, H=128
#define TT 2048
#define EE 1024
#define HH 128
#define UPB 288   // partial slots per batch: sum over 64 qtiles of (qt>>3)+1

typedef __attribute__((address_space(3))) void lds_void_t;
typedef const __attribute__((address_space(1))) void gbl_void_t;

// ---------------- prep: Wt[w][n][k] = W[w][k][n], f32 -> bf16 ----------------
__global__ __launch_bounds__(256) void prep_w_kernel(
    const float* __restrict__ Wq, const float* __restrict__ Wk,
    const float* __restrict__ Wv, bf16_t* __restrict__ Wt)
{
    int idx = blockIdx.x * 256 + threadIdx.x;   // 0 .. 3*131072-1
    int w = idx >> 17;
    int r = idx & 131071;                        // n*1024 + k
    int n = r >> 10, k = r & 1023;
    const float* W = (w == 0) ? Wq : (w == 1) ? Wk : Wv;
    Wt[idx] = (bf16_t)W[k * HH + n];
}

// ---------------- fused QKV GEMM: [16384 x 1024] x [1024 x 384] ----------------
// 512 blocks (2/CU) x 256 thr (4 waves); tile 64 rows x 192 cols; wave 32x96.
// A (f32) staged via global_load_lds w/ XOR-swizzled source (linear dest,
// swizzled ds_read -> conflict-free); LDS dbuf; stage issued BEFORE compute;
// W-frags register-prefetched one K-step ahead.
__global__ __launch_bounds__(256) void qkv_kernel(
    const float* __restrict__ x, const bf16_t* __restrict__ Wt,
    bf16_t* __restrict__ Q, bf16_t* __restrict__ Ko, bf16_t* __restrict__ Vt)
{
    __shared__ __attribute__((aligned(16))) float Al[2][64][32];
    const int bx = blockIdx.x;
    const int row0   = (bx >> 1) * 64;
    const int nhalf  = bx & 1;                   // 192-col half of 384
    const int tid  = threadIdx.x;
    const int lane = tid & 63;
    const int wid  = tid >> 6;
    const int wm = wid >> 1, wn = wid & 1;       // wave = 32 rows x 96 cols
    const int g = lane >> 4, c = lane & 15;

    const bf16_t* wrow[6];
    for (int nt = 0; nt < 6; ++nt) {
        int cb = nhalf * 192 + wn * 96 + nt * 16;
        wrow[nt] = Wt + ((size_t)(cb >> 7) * HH + (cb & 127) + c) * EE + g * 8;
    }

    f32x4 acc[2][6];
    for (int i = 0; i < 2; ++i)
        for (int j = 0; j < 6; ++j) acc[i][j] = (f32x4)0.0f;

#define QSTAGE(T, BUF) do {                                                   \
    for (int is = 0; is < 2; ++is) {                                          \
        int slot = is * 256 + tid;                                            \
        int arow = slot >> 3, ach = slot & 7;                                 \
        const float* asrc = x + (size_t)(row0 + arow) * EE + (T) * 32 +       \
                            ((ach ^ (arow & 7)) * 4);                         \
        __builtin_amdgcn_global_load_lds((gbl_void_t*)asrc,                   \
            (lds_void_t*)((char*)&Al[BUF][0][0] + is * 4096 + wid * 1024),    \
            16, 0, 0);                                                        \
    } } while (0)

#define WLOAD(WREG, T)                                                        \
    for (int nt = 0; nt < 6; ++nt)                                            \
        WREG[nt] = *(const bf16x8*)(wrow[nt] + (size_t)(T) * 32);

#define QCOMPUTE(BUF, WREG) do {                                              \
    for (int mt = 0; mt < 2; ++mt) {                                          \
        const char* rb_ = (const char*)&Al[BUF][wm * 32 + mt * 16 + c][0];    \
        f32x4 r0_ = *(const f32x4*)(rb_ + (((2 * g) ^ (c & 7)) << 4));        \
        f32x4 r1_ = *(const f32x4*)(rb_ + (((2 * g + 1) ^ (c & 7)) << 4));    \
        union { bf16_t h[8]; bf16x8 v; } u_;                                  \
        for (int jj = 0; jj < 4; ++jj) {                                      \
            u_.h[jj]     = (bf16_t)r0_[jj];                                   \
            u_.h[4 + jj] = (bf16_t)r1_[jj];                                   \
        }                                                                     \
        for (int nt = 0; nt < 6; ++nt)                                        \
            acc[mt][nt] = MFMA16(u_.v, WREG[nt], acc[mt][nt]);                \
    } } while (0)

    bf16x8 wA[6], wB[6];
    QSTAGE(0, 0);
    WLOAD(wA, 0);
    __syncthreads();

    for (int t = 0; t < 32; t += 2) {
        if (t + 1 < 32) { QSTAGE(t + 1, 1); WLOAD(wB, t + 1); }
        QCOMPUTE(0, wA);
        __syncthreads();
        if (t + 2 < 32) { QSTAGE(t + 2, 0); WLOAD(wA, t + 2); }
        QCOMPUTE(1, wB);
        __syncthreads();
    }
#undef QSTAGE
#undef WLOAD
#undef QCOMPUTE

    const float sc = 0.08838834764831845f * 1.4426950408889634f; // 1/sqrt(128)*log2e
    const int b  = row0 >> 11;
    const int tb = row0 & (TT - 1);
    for (int mt = 0; mt < 2; ++mt)
        for (int nt = 0; nt < 6; ++nt) {
            int cb = nhalf * 192 + wn * 96 + nt * 16;
            int w  = cb >> 7;
            int h  = (cb & 127) + c;
            int t0 = row0 + wm * 32 + mt * 16 + g * 4;
            if (w == 0) {
                for (int i = 0; i < 4; ++i)
                    Q[(size_t)(t0 + i) * HH + h] = (bf16_t)(acc[mt][nt][i] * sc);
            } else if (w == 1) {
                for (int i = 0; i < 4; ++i)
                    Ko[(size_t)(t0 + i) * HH + h] = (bf16_t)acc[mt][nt][i];
            } else {
                union { bf16_t h4[4]; unsigned long long u; } pk;
                for (int i = 0; i < 4; ++i) pk.h4[i] = (bf16_t)acc[mt][nt][i];
                *reinterpret_cast<unsigned long long*>(
                    Vt + ((size_t)(b * HH + h)) * TT + tb + wm * 32 + mt * 16 + g * 4) = pk.u;
            }
        }
}

// ---------------- flash attention, block-cooperative split-KV ----------------
// block = (b, 128-row q-band j, 256-kv chunk ch); 4 waves each own 32 q-rows,
// SHARE the chunk: K[32][128] + V^T[128][32] staged per 32-kv subtile via
// swizzled global_load_lds, double-buffered, 2-phase (stage next, compute cur).
// bx&7 = b -> XCD-pinned batch. Partial-slot (sid) scheme unchanged.
__global__ __launch_bounds__(256) void attn_kernel(
    const bf16_t* __restrict__ Q, const bf16_t* __restrict__ K,
    const bf16_t* __restrict__ V, bf16_t* __restrict__ Pacc,
    float* __restrict__ Pml)
{
    __shared__ __attribute__((aligned(16))) bf16_t Kl[2][32][128];
    __shared__ __attribute__((aligned(16))) bf16_t Vl[2][128][32];
    __shared__ __attribute__((aligned(16))) bf16_t Pl[4][32][40];
    const int tid = threadIdx.x, lane = tid & 63, wid = tid >> 6;
    const int g = lane >> 4, c = lane & 15;
    bf16_t (*P)[40] = Pl[wid];

    const int bx = blockIdx.x;
    const int b  = bx & 7;                       // XCD-pinned batch
    const int u  = bx >> 3;                      // 0..71, long blocks first
    int j = 15, rem = u;
    while (rem >= ((j >> 1) + 1)) { rem -= (j >> 1) + 1; --j; }
    const int ch = rem;
    const int kv_lo  = ch * 256;
    int blk_hi = kv_lo + 256;
    if (blk_hi > j * 128 + 128) blk_hi = j * 128 + 128;
    const int ntb = (blk_hi - kv_lo) >> 5;       // 1..8 subtiles, block-uniform

    const int qt = j * 4 + wid;                  // this wave's 32-row q-tile
    const int q0 = qt * 32;
    int kv_hi_w = kv_lo + 256;
    if (kv_hi_w > q0 + 32) kv_hi_w = q0 + 32;    // causal limit (wave-uniform)
    const int k  = qt >> 3;
    const int sid = b * UPB + 4 * k * (k + 1) + (qt & 7) * (k + 1) + ch;

    const bf16_t* Qb = Q + (size_t)b * TT * HH;
    const bf16_t* Kb = K + (size_t)b * TT * HH;
    const bf16_t* Vb = V + (size_t)b * HH * TT;

#define ASTAGE(T, BUF) do {                                                   \
    const int kv0_ = kv_lo + (T) * 32;                                        \
    for (int is = 0; is < 2; ++is) {                                          \
        int slot = is * 256 + tid;                                            \
        int krow = slot >> 4, kch = slot & 15;                                \
        const bf16_t* ksrc = Kb + (size_t)(kv0_ + krow) * HH +                \
                             ((kch ^ (krow & 7)) * 8);                        \
        __builtin_amdgcn_global_load_lds((gbl_void_t*)ksrc,                   \
            (lds_void_t*)((char*)&Kl[BUF][0][0] + is * 4096 + wid * 1024),    \
            16, 0, 0);                                                        \
        int vrow = slot >> 2, vch = slot & 3;                                 \
        const bf16_t* vsrc = Vb + (size_t)vrow * TT + kv0_ +                  \
                             ((vch ^ (vrow & 3)) * 8);                        \
        __builtin_amdgcn_global_load_lds((gbl_void_t*)vsrc,                   \
            (lds_void_t*)((char*)&Vl[BUF][0][0] + is * 4096 + wid * 1024),    \
            16, 0, 0);                                                        \
    } } while (0)

    bf16x8 qA[4], qB[4];
    for (int kk = 0; kk < 4; ++kk) {
        qA[kk] = *(const bf16x8*)(Qb + (size_t)(q0 + c) * HH + kk * 32 + g * 8);
        qB[kk] = *(const bf16x8*)(Qb + (size_t)(q0 + 16 + c) * HH + kk * 32 + g * 8);
    }

    f32x4 accA[8], accB[8];
    for (int hb = 0; hb < 8; ++hb) { accA[hb] = (f32x4)0.0f; accB[hb] = (f32x4)0.0f; }
    float lsA[4] = {0, 0, 0, 0}, lsB[4] = {0, 0, 0, 0};

    ASTAGE(0, 0);
    __syncthreads();
    int buf = 0;
    for (int t = 0; t < ntb; ++t) {
        if (t + 1 < ntb) ASTAGE(t + 1, buf ^ 1);
        const int kv0 = kv_lo + t * 32;
        if (kv0 < kv_hi_w) {                     // wave-uniform causal skip
            bf16x8 k0f[4], k1f[4], vf[8];
            for (int kk = 0; kk < 4; ++kk) {
                k0f[kk] = *(const bf16x8*)&Kl[buf][c][((kk * 4 + g) ^ (c & 7)) * 8];
                k1f[kk] = *(const bf16x8*)&Kl[buf][16 + c][((kk * 4 + g) ^ (c & 7)) * 8];
            }
            for (int hb = 0; hb < 8; ++hb)
                vf[hb] = *(const bf16x8*)&Vl[buf][hb * 16 + c][(g ^ (c & 3)) * 8];

            f32x4 sA0 = (f32x4)0.0f, sA1 = (f32x4)0.0f;
            f32x4 sB0 = (f32x4)0.0f, sB1 = (f32x4)0.0f;
            for (int kk = 0; kk < 4; ++kk) {
                sA0 = MFMA16(qA[kk], k0f[kk], sA0);
                sA1 = MFMA16(qA[kk], k1f[kk], sA1);
                sB0 = MFMA16(qB[kk], k0f[kk], sB0);
                sB1 = MFMA16(qB[kk], k1f[kk], sB1);
            }
            if (kv0 + 32 > q0) {                 // causal mask, subtile A
                for (int i = 0; i < 4; ++i) {
                    int row = q0 + g * 4 + i;
                    if (kv0 + c > row)      sA0[i] = -1e30f;
                    if (kv0 + 16 + c > row) sA1[i] = -1e30f;
                }
            }
            if (kv0 + 32 > q0 + 16) {            // causal mask, subtile B
                for (int i = 0; i < 4; ++i) {
                    int row = q0 + 16 + g * 4 + i;
                    if (kv0 + c > row)      sB0[i] = -1e30f;
                    if (kv0 + 16 + c > row) sB1[i] = -1e30f;
                }
            }
            float pA0[4], pA1[4], pB0[4], pB1[4];
            for (int i = 0; i < 4; ++i) {        // p = 2^s (log2e folded into Q)
                pA0[i] = exp2f(sA0[i]); pA1[i] = exp2f(sA1[i]);
                pB0[i] = exp2f(sB0[i]); pB1[i] = exp2f(sB1[i]);
                lsA[i] += pA0[i] + pA1[i];
                lsB[i] += pB0[i] + pB1[i];
            }
            for (int i = 0; i < 4; ++i) {
                P[g * 4 + i][c]           = (bf16_t)pA0[i];
                P[g * 4 + i][c + 16]      = (bf16_t)pA1[i];
                P[16 + g * 4 + i][c]      = (bf16_t)pB0[i];
                P[16 + g * 4 + i][c + 16] = (bf16_t)pB1[i];
            }
            __builtin_amdgcn_wave_barrier();
            asm volatile("s_waitcnt lgkmcnt(0)" ::: "memory");
            __builtin_amdgcn_sched_barrier(0);
            bf16x8 paA = *(const bf16x8*)&P[c][g * 8];
            bf16x8 paB = *(const bf16x8*)&P[16 + c][g * 8];
            for (int hb = 0; hb < 8; ++hb) {
                accA[hb] = MFMA16(paA, vf[hb], accA[hb]);
                accB[hb] = MFMA16(paB, vf[hb], accB[hb]);
            }
            __builtin_amdgcn_wave_barrier();
        }
        __syncthreads();
        buf ^= 1;
    }
#undef ASTAGE

    for (int off = 1; off < 16; off <<= 1)
        for (int i = 0; i < 4; ++i) {
            lsA[i] += __shfl_xor(lsA[i], off, 64);
            lsB[i] += __shfl_xor(lsB[i], off, 64);
        }
    if (c == 0)
        for (int i = 0; i < 4; ++i) {
            Pml[(size_t)sid * 32 + g * 4 + i]      = lsA[i];
            Pml[(size_t)sid * 32 + 16 + g * 4 + i] = lsB[i];
        }

    bf16_t* po = Pacc + (size_t)sid * (32 * 128);
    for (int hb = 0; hb < 8; ++hb)
        for (int i = 0; i < 4; ++i) {
            po[(g * 4 + i) * 128 + hb * 16 + c]      = (bf16_t)accA[hb][i];
            po[(16 + g * 4 + i) * 128 + hb * 16 + c] = (bf16_t)accB[hb][i];
        }
}

// ---------------- combine partials (plain sums) ----------------
__global__ __launch_bounds__(128) void combine_kernel(
    const bf16_t* __restrict__ Pacc, const float* __restrict__ Pml,
    float* __restrict__ out)
{
    __shared__ float invL[32];
    const int qt = blockIdx.x;                   // 0..63
    const int b  = blockIdx.y;
    const int k  = qt >> 3;
    const int base  = b * UPB + 4 * k * (k + 1) + (qt & 7) * (k + 1);
    const int count = k + 1;
    const int tid = threadIdx.x;

    if (tid < 32) {
        float L = 0.0f;
        for (int cu = 0; cu < count; ++cu)
            L += Pml[(size_t)(base + cu) * 32 + tid];
        invL[tid] = 1.0f / L;
    }
    __syncthreads();

    const int cg = tid & 31, rs = tid >> 5;
    const int q0 = qt * 32;
    for (int rr = 0; rr < 8; ++rr) {
        int row = rr * 4 + rs;
        float s0 = 0.f, s1 = 0.f, s2 = 0.f, s3 = 0.f;
        for (int cu = 0; cu < count; ++cu) {
            bf16x4 v = *(const bf16x4*)(
                Pacc + (size_t)(base + cu) * 4096 + row * 128 + cg * 4);
            s0 += (float)v[0]; s1 += (float)v[1];
            s2 += (float)v[2]; s3 += (float)v[3];
        }
        float iv = invL[row];
        *reinterpret_cast<float4*>(
            out + ((size_t)b * TT + q0 + row) * HH + cg * 4) =
            make_float4(s0 * iv, s1 * iv, s2 * iv, s3 * iv);
    }
}

extern "C" void kernel_launch(void* const* d_in, const int* in_sizes, int n_in,
                              void* d_out, int out_size, void* d_ws, size_t ws_size,
                              hipStream_t stream)
{
    const float* x  = (const float*)d_in[0];
    const float* Wq = (const float*)d_in[1];
    const float* Wk = (const float*)d_in[2];
    const float* Wv = (const float*)d_in[3];

    char* ws = (char*)d_ws;
    bf16_t* Wt   = (bf16_t*)ws;                       // 768 KB
    bf16_t* Qb   = (bf16_t*)(ws + (1u  << 20));       // 4 MB
    bf16_t* Kb   = (bf16_t*)(ws + (5u  << 20));       // 4 MB
    bf16_t* Vt   = (bf16_t*)(ws + (9u  << 20));       // 4 MB
    bf16_t* Pacc = (bf16_t*)(ws + (13u << 20));       // 2304*8192 B = 18.9 MB
    float*  Pml  = (float*) (ws + (32u << 20));       // 2304*128 B

    prep_w_kernel<<<1536, 256, 0, stream>>>(Wq, Wk, Wv, Wt);
    qkv_kernel<<<512, 256, 0, stream>>>(x, Wt, Qb, Kb, Vt);
    attn_kernel<<<576, 256, 0, stream>>>(Qb, Kb, Vt, Pacc, Pml);
    combine_kernel<<<dim3(64, 8), 128, 0, stream>>>(Pacc, Pml, (float*)d_out);
}

// Round 9
// 80.789 us; speedup vs baseline: 1.6037x; 1.6037x over previous
//
#include <hip/hip_runtime.h>
#include <hip/hip_bf16.h>

typedef __bf16 bf16_t;
typedef bf16_t bf16x8 __attribute__((ext_vector_type(8)));
typedef bf16_t bf16x4 __attribute__((ext_vector_type(4)));
typedef float f32x4 __attribute__((ext_vector_type(4)));

#define MFMA16(a, b, c) __builtin_amdgcn_mfma_f32_16x16x32_bf16((a), (b), (c), 0, 0, 0)

// B=8, T=2048, E=1024, H=128
#define TT 2048
#define EE 1024
#define HH 128
#define UPB 288   // partial slots per batch: sum over 64 qtiles of (qt>>3)+1

// Fragment-major layouts (consumer = attn MFMA fragments, 1 coalesced load each):
//  Qf/Kf: chunk(grt, kk) = 64 lanes x 16B; lane g*16+c elem e = M[grt*16+c][kk*32+g*8+e]
//  Vf:    chunk(b, vc, hb) = 64 lanes x 16B; lane g*16+c elem j = V[b][vc*32+g*8+j][hb*16+c]

// ---------------- prep: Wt[w][n][k] = W[w][k][n], f32 -> bf16 ----------------
__global__ __launch_bounds__(256) void prep_w_kernel(
    const float* __restrict__ Wq, const float* __restrict__ Wk,
    const float* __restrict__ Wv, bf16_t* __restrict__ Wt)
{
    int idx = blockIdx.x * 256 + threadIdx.x;   // 0 .. 3*131072-1
    int w = idx >> 17;
    int r = idx & 131071;                        // n*1024 + k
    int n = r >> 10, k = r & 1023;
    const float* W = (w == 0) ? Wq : (w == 1) ? Wk : Wv;
    Wt[idx] = (bf16_t)W[k * HH + n];
}

// ---------------- fused QKV GEMM: [16384 x 1024] x [1024 x 384] ----------------
// R7 structure (53us known-good): 256 blocks (1/CU) x 256 thr (4 waves);
// tile 64 rows x 384 cols; wave 64x96; x read ONCE, reg-staged f32->bf16
// (loads early, write late), LDS dbuf, one barrier per K-tile; W-frags
// double-reg-prefetched. Epilogue writes FRAGMENT-MAJOR Qf/Kf/Vf.
__global__ __launch_bounds__(256) void qkv_kernel(
    const float* __restrict__ x, const bf16_t* __restrict__ Wt,
    bf16_t* __restrict__ Qf, bf16_t* __restrict__ Kf, bf16_t* __restrict__ Vf)
{
    __shared__ __attribute__((aligned(16))) bf16_t As[2][64][40];
    const int row0 = blockIdx.x * 64;
    const int tid  = threadIdx.x;
    const int lane = tid & 63;
    const int wn   = tid >> 6;                    // 4 waves: 96-col slices
    const int g = lane >> 4, c = lane & 15;

    const int row_a = tid >> 3;                   // 0..31
    const int row_b = 32 + row_a;
    const int col4  = (tid & 7) * 4;
    const float* xA = x + (size_t)(row0 + row_a) * EE + col4;
    const float* xB = x + (size_t)(row0 + row_b) * EE + col4;

    const bf16_t* wrow[6];
    for (int nt = 0; nt < 6; ++nt) {
        int cb = wn * 96 + nt * 16;
        wrow[nt] = Wt + ((size_t)(cb >> 7) * HH + (cb & 127) + c) * EE + g * 8;
    }

    f32x4 acc[4][6];
    for (int i = 0; i < 4; ++i)
        for (int j = 0; j < 6; ++j) acc[i][j] = (f32x4)0.0f;

    float4 f0, f1;
#define STAGE_LOAD(T) do {                                                    \
    f0 = *reinterpret_cast<const float4*>(xA + (size_t)(T) * 32);             \
    f1 = *reinterpret_cast<const float4*>(xB + (size_t)(T) * 32);             \
} while (0)
#define STAGE_WRITE(BUF) do {                                                 \
    union { bf16_t h[4]; unsigned long long u; } p0, p1;                      \
    p0.h[0] = (bf16_t)f0.x; p0.h[1] = (bf16_t)f0.y;                           \
    p0.h[2] = (bf16_t)f0.z; p0.h[3] = (bf16_t)f0.w;                           \
    p1.h[0] = (bf16_t)f1.x; p1.h[1] = (bf16_t)f1.y;                           \
    p1.h[2] = (bf16_t)f1.z; p1.h[3] = (bf16_t)f1.w;                           \
    *reinterpret_cast<unsigned long long*>(&As[BUF][row_a][col4]) = p0.u;     \
    *reinterpret_cast<unsigned long long*>(&As[BUF][row_b][col4]) = p1.u;     \
} while (0)
#define COMPUTE(BUF, WREG) do {                                               \
    for (int mt = 0; mt < 4; ++mt) {                                          \
        bf16x8 af = *reinterpret_cast<const bf16x8*>(&As[BUF][mt * 16 + c][g * 8]); \
        for (int nt = 0; nt < 6; ++nt)                                        \
            acc[mt][nt] = MFMA16(af, WREG[nt], acc[mt][nt]);                  \
    } } while (0)

    bf16x8 wA[6], wB[6];
    for (int nt = 0; nt < 6; ++nt) wA[nt] = *(const bf16x8*)(wrow[nt]);
    STAGE_LOAD(0);
    STAGE_WRITE(0);
    __syncthreads();

    for (int t = 0; t < 32; t += 2) {
        if (t + 1 < 32) {
            STAGE_LOAD(t + 1);
            for (int nt = 0; nt < 6; ++nt)
                wB[nt] = *(const bf16x8*)(wrow[nt] + (size_t)(t + 1) * 32);
        }
        COMPUTE(0, wA);
        if (t + 1 < 32) STAGE_WRITE(1);
        __syncthreads();
        if (t + 1 >= 32) break;

        if (t + 2 < 32) {
            STAGE_LOAD(t + 2);
            for (int nt = 0; nt < 6; ++nt)
                wA[nt] = *(const bf16x8*)(wrow[nt] + (size_t)(t + 2) * 32);
        }
        COMPUTE(1, wB);
        if (t + 2 < 32) STAGE_WRITE(0);
        __syncthreads();
    }
#undef STAGE_LOAD
#undef STAGE_WRITE
#undef COMPUTE

    const float sc = 0.08838834764831845f * 1.4426950408889634f; // 1/sqrt(128)*log2e
    for (int mt = 0; mt < 4; ++mt)
        for (int nt = 0; nt < 6; ++nt) {
            int cb = wn * 96 + nt * 16;
            int w  = cb >> 7;
            int hl = (cb & 127) + c;             // col within Q/K/V
            int t0 = row0 + mt * 16 + g * 4;     // global row
            if (w == 2) {
                // V fragment-major: pack 4 consecutive rows (same chunk, j0..j0+3)
                int b  = t0 >> 11;
                int t  = t0 & (TT - 1);
                int vc = t >> 5, gg = (t & 31) >> 3, j0 = t & 7;
                int hb = hl >> 4, cc = hl & 15;
                union { bf16_t h4[4]; unsigned long long u; } pk;
                for (int i = 0; i < 4; ++i) pk.h4[i] = (bf16_t)acc[mt][nt][i];
                *reinterpret_cast<unsigned long long*>(
                    Vf + ((size_t)((b * 64 + vc) * 8 + hb)) * 512 +
                    (gg * 16 + cc) * 8 + j0) = pk.u;
            } else {
                bf16_t* dst = (w == 0) ? Qf : Kf;
                float s = (w == 0) ? sc : 1.0f;
                int kk = hl >> 5, gg = (hl & 31) >> 3, e = hl & 7;
                int grt = t0 >> 4;               // g*4+i stays within the tile
                for (int i = 0; i < 4; ++i) {
                    int cr = (t0 + i) & 15;
                    dst[((size_t)(grt * 4 + kk)) * 512 + (gg * 16 + cr) * 8 + e] =
                        (bf16_t)(acc[mt][nt][i] * s);
                }
            }
        }
}

// ---------------- flash attention, split-KV partials, fragment-major I/O ----------------
// unit = (b, 32-row qtile, kvchunk256); one wave per unit, 4 units/block.
// blockIdx&7 = b -> XCD-pinned batch. Every Q/K/V load = 1 coalesced 1KB instr.
__global__ __launch_bounds__(256) void attn_kernel(
    const bf16_t* __restrict__ Qf, const bf16_t* __restrict__ Kf,
    const bf16_t* __restrict__ Vf, bf16_t* __restrict__ Pacc,
    float* __restrict__ Pml)
{
    __shared__ __attribute__((aligned(16))) bf16_t Pl[4][32][40];
    const int tid = threadIdx.x, lane = tid & 63, wid = tid >> 6;
    const int g = lane >> 4, c = lane & 15;
    bf16_t (*P)[40] = Pl[wid];

    const int bx = blockIdx.x;
    const int b  = bx & 7;                       // XCD-pinned batch
    const int u  = 287 - ((bx >> 3) * 4 + wid);  // long-units-first
    int k = 0;
    while (4 * (k + 1) * (k + 2) <= u) ++k;      // tier k = qt>>3, 0..7
    const int r  = u - 4 * k * (k + 1);
    const int qt = 8 * k + r / (k + 1);
    const int ch = r - (r / (k + 1)) * (k + 1);
    const int q0 = qt * 32;
    const int kv_lo = ch * 256;
    int kv_hi = kv_lo + 256; if (kv_hi > q0 + 32) kv_hi = q0 + 32;
    const int sid = b * UPB + 4 * k * (k + 1) + (qt & 7) * (k + 1) + ch;

    bf16x8 qA[4], qB[4];
    for (int kk = 0; kk < 4; ++kk) {
        qA[kk] = *(const bf16x8*)(Qf +
            ((size_t)((b * 128 + (q0 >> 4)) * 4 + kk)) * 512 + lane * 8);
        qB[kk] = *(const bf16x8*)(Qf +
            ((size_t)((b * 128 + (q0 >> 4) + 1) * 4 + kk)) * 512 + lane * 8);
    }

    f32x4 accA[8], accB[8];
    for (int hb = 0; hb < 8; ++hb) { accA[hb] = (f32x4)0.0f; accB[hb] = (f32x4)0.0f; }
    float lsA[4] = {0, 0, 0, 0}, lsB[4] = {0, 0, 0, 0};

    for (int kv0 = kv_lo; kv0 < kv_hi; kv0 += 32) {
        const int kt = b * 128 + (kv0 >> 4);
        bf16x8 k0f[4], k1f[4], vf[8];
        for (int kk = 0; kk < 4; ++kk) {
            k0f[kk] = *(const bf16x8*)(Kf + ((size_t)(kt * 4 + kk)) * 512 + lane * 8);
            k1f[kk] = *(const bf16x8*)(Kf + ((size_t)((kt + 1) * 4 + kk)) * 512 + lane * 8);
        }
        const int vcb = (b * 64 + (kv0 >> 5)) * 8;
        for (int hb = 0; hb < 8; ++hb)
            vf[hb] = *(const bf16x8*)(Vf + ((size_t)(vcb + hb)) * 512 + lane * 8);

        f32x4 sA0 = (f32x4)0.0f, sA1 = (f32x4)0.0f;
        f32x4 sB0 = (f32x4)0.0f, sB1 = (f32x4)0.0f;
        for (int kk = 0; kk < 4; ++kk) {
            sA0 = MFMA16(qA[kk], k0f[kk], sA0);
            sA1 = MFMA16(qA[kk], k1f[kk], sA1);
            sB0 = MFMA16(qB[kk], k0f[kk], sB0);
            sB1 = MFMA16(qB[kk], k1f[kk], sB1);
        }
        if (kv0 + 32 > q0) {                     // causal mask, subtile A
            for (int i = 0; i < 4; ++i) {
                int row = q0 + g * 4 + i;
                if (kv0 + c > row)      sA0[i] = -1e30f;
                if (kv0 + 16 + c > row) sA1[i] = -1e30f;
            }
        }
        if (kv0 + 32 > q0 + 16) {                // causal mask, subtile B
            for (int i = 0; i < 4; ++i) {
                int row = q0 + 16 + g * 4 + i;
                if (kv0 + c > row)      sB0[i] = -1e30f;
                if (kv0 + 16 + c > row) sB1[i] = -1e30f;
            }
        }
        float pA0[4], pA1[4], pB0[4], pB1[4];
        for (int i = 0; i < 4; ++i) {            // p = 2^s (log2e folded into Q)
            pA0[i] = exp2f(sA0[i]); pA1[i] = exp2f(sA1[i]);
            pB0[i] = exp2f(sB0[i]); pB1[i] = exp2f(sB1[i]);
            lsA[i] += pA0[i] + pA1[i];
            lsB[i] += pB0[i] + pB1[i];
        }
        for (int i = 0; i < 4; ++i) {
            P[g * 4 + i][c]           = (bf16_t)pA0[i];
            P[g * 4 + i][c + 16]      = (bf16_t)pA1[i];
            P[16 + g * 4 + i][c]      = (bf16_t)pB0[i];
            P[16 + g * 4 + i][c + 16] = (bf16_t)pB1[i];
        }
        __builtin_amdgcn_wave_barrier();
        asm volatile("s_waitcnt lgkmcnt(0)" ::: "memory");
        __builtin_amdgcn_sched_barrier(0);
        bf16x8 paA = *(const bf16x8*)&P[c][g * 8];
        bf16x8 paB = *(const bf16x8*)&P[16 + c][g * 8];
        __builtin_amdgcn_s_setprio(1);
        for (int hb = 0; hb < 8; ++hb) {
            accA[hb] = MFMA16(paA, vf[hb], accA[hb]);
            accB[hb] = MFMA16(paB, vf[hb], accB[hb]);
        }
        __builtin_amdgcn_s_setprio(0);
        __builtin_amdgcn_wave_barrier();
    }

    for (int off = 1; off < 16; off <<= 1)
        for (int i = 0; i < 4; ++i) {
            lsA[i] += __shfl_xor(lsA[i], off, 64);
            lsB[i] += __shfl_xor(lsB[i], off, 64);
        }
    if (c == 0)
        for (int i = 0; i < 4; ++i) {
            Pml[(size_t)sid * 32 + g * 4 + i]      = lsA[i];
            Pml[(size_t)sid * 32 + 16 + g * 4 + i] = lsB[i];
        }

    // Pacc transposed: po[col=128][row=32]; packed 8B stores
    bf16_t* po = Pacc + (size_t)sid * (32 * 128);
    for (int hb = 0; hb < 8; ++hb) {
        union { bf16_t h4[4]; unsigned long long u; } pa, pb;
        for (int i = 0; i < 4; ++i) {
            pa.h4[i] = (bf16_t)accA[hb][i];
            pb.h4[i] = (bf16_t)accB[hb][i];
        }
        bf16_t* cp = po + (hb * 16 + c) * 32;
        *reinterpret_cast<unsigned long long*>(cp + g * 4)      = pa.u;
        *reinterpret_cast<unsigned long long*>(cp + 16 + g * 4) = pb.u;
    }
}

// ---------------- combine partials (plain sums; Pacc is [col][row]) ----------------
__global__ __launch_bounds__(128) void combine_kernel(
    const bf16_t* __restrict__ Pacc, const float* __restrict__ Pml,
    float* __restrict__ out)
{
    __shared__ float invL[32];
    const int qt = blockIdx.x;                   // 0..63
    const int b  = blockIdx.y;
    const int k  = qt >> 3;
    const int base  = b * UPB + 4 * k * (k + 1) + (qt & 7) * (k + 1);
    const int count = k + 1;
    const int tid = threadIdx.x;                 // = col 0..127

    if (tid < 32) {
        float L = 0.0f;
        for (int cu = 0; cu < count; ++cu)
            L += Pml[(size_t)(base + cu) * 32 + tid];
        invL[tid] = 1.0f / L;
    }
    __syncthreads();

    float s[32];
    for (int r = 0; r < 32; ++r) s[r] = 0.0f;
    for (int cu = 0; cu < count; ++cu) {
        const bf16_t* cp = Pacc + (size_t)(base + cu) * 4096 + tid * 32;
        for (int r8 = 0; r8 < 4; ++r8) {
            bf16x8 v = *(const bf16x8*)(cp + r8 * 8);
            for (int j = 0; j < 8; ++j) s[r8 * 8 + j] += (float)v[j];
        }
    }
    const int q0 = qt * 32;
    for (int r = 0; r < 32; ++r)
        out[((size_t)b * TT + q0 + r) * HH + tid] = s[r] * invL[r];
}

extern "C" void kernel_launch(void* const* d_in, const int* in_sizes, int n_in,
                              void* d_out, int out_size, void* d_ws, size_t ws_size,
                              hipStream_t stream)
{
    const float* x  = (const float*)d_in[0];
    const float* Wq = (const float*)d_in[1];
    const float* Wk = (const float*)d_in[2];
    const float* Wv = (const float*)d_in[3];

    char* ws = (char*)d_ws;
    bf16_t* Wt   = (bf16_t*)ws;                       // 768 KB
    bf16_t* Qf   = (bf16_t*)(ws + (1u  << 20));       // 4 MB fragment-major
    bf16_t* Kf   = (bf16_t*)(ws + (5u  << 20));       // 4 MB fragment-major
    bf16_t* Vf   = (bf16_t*)(ws + (9u  << 20));       // 4 MB fragment-major
    bf16_t* Pacc = (bf16_t*)(ws + (13u << 20));       // 2304*8192 B = 18.9 MB
    float*  Pml  = (float*) (ws + (32u << 20));       // 2304*128 B

    prep_w_kernel<<<1536, 256, 0, stream>>>(Wq, Wk, Wv, Wt);
    qkv_kernel<<<256, 256, 0, stream>>>(x, Wt, Qf, Kf, Vf);
    attn_kernel<<<576, 256, 0, stream>>>(Qf, Kf, Vf, Pacc, Pml);
    combine_kernel<<<dim3(64, 8), 128, 0, stream>>>(Pacc, Pml, (float*)d_out);
}